// Round 8
// baseline (111.947 us; speedup 1.0000x reference)
//
#include <hip/hip_runtime.h>

// Problem constants (reference: N=32768, M=8192, D=64, fp32)
#define N_ROWS 32768
#define M_COLS 8192
#define D_DIM  64
#define JC     16                     // j-chunks (grid.y) — 2048 blocks, no 4/CU quantization
#define PBLOCK 256                    // prep block size
#define BLOCK  256                    // partial_min: 4 waves/block
#define RBLOCK 128                    // reduce block size (256 blocks -> all CUs)
#define GROUPS 2                      // 32-row i-groups per wave -> 64 i/wave
#define ROWS_PER_BLOCK 256            // 4 waves x 64 i; grid = 128 x JC
#define CHUNK  (M_COLS / JC)          // 512 j per chunk
#define NJJ    (CHUNK / 32)           // 16 j-blocks per chunk

typedef _Float16 v8h  __attribute__((ext_vector_type(8)));
typedef _Float16 v4h  __attribute__((ext_vector_type(4)));
typedef float    v16f __attribute__((ext_vector_type(16)));

// ---------- kernel 1: yhT=(half)y in FRAGMENT-MAJOR layout, th, xh, x2 ----------
// yhT layout: half-index = (j>>5)*2048 + (k>>3)*256 + (j&31)*8 + (k&7).
// A partial_min wave's B-slice load (32 lanes x v8h) is then 1 KB CONTIGUOUS
// (R6 lesson: row-major per-lane loads strided 128 B -> ~32 transactions/instr).
__global__ __launch_bounds__(PBLOCK) void prep_kernel(
    const float* __restrict__ y, const float* __restrict__ psi,
    const float* __restrict__ x, _Float16* __restrict__ yhT,
    float* __restrict__ th, _Float16* __restrict__ xh,
    float* __restrict__ x2, float* __restrict__ out) {
    const int tid = threadIdx.x;
    const int bid = blockIdx.x;
    const int n = tid & 15;                      // 4-elem segment (k = n*4 .. n*4+3)
    if (bid < M_COLS / 16) {
        if (bid == 0 && tid == 0) out[0] = 0.f;  // atomic accumulator init
        const int j = bid * 16 + (tid >> 4);     // y row
        const float4 v = *(const float4*)(y + (size_t)j * D_DIM + n * 4);
        float s = v.x * v.x + v.y * v.y + v.z * v.z + v.w * v.w;
        v4h hv = { (_Float16)v.x, (_Float16)v.y, (_Float16)v.z, (_Float16)v.w };
        // fragment-major: octet o = (n*4)>>3 = n>>1, elem base = (n&1)*4
        *(v4h*)(yhT + (size_t)(j >> 5) * 2048 + (n >> 1) * 256
                    + (j & 31) * 8 + (n & 1) * 4) = hv;
#pragma unroll
        for (int m = 1; m < 16; m <<= 1) s += __shfl_xor(s, m, 64);
        if (n == 0) th[j] = 0.5f * (psi[j] - s);
    } else {
        const int i = (bid - M_COLS / 16) * 16 + (tid >> 4);  // x row
        const float4 v = *(const float4*)(x + (size_t)i * D_DIM + n * 4);
        float s = v.x * v.x + v.y * v.y + v.z * v.z + v.w * v.w;
        v4h hv = { (_Float16)v.x, (_Float16)v.y, (_Float16)v.z, (_Float16)v.w };
        *(v4h*)(xh + (size_t)i * D_DIM + n * 4) = hv;
#pragma unroll
        for (int m = 1; m < 16; m <<= 1) s += __shfl_xor(s, m, 64);
        if (n == 0) x2[i] = s;                     // reduce no longer re-reads 8 MB of x
    }
}

// ---------- kernel 2: MFMA partial min over a j-chunk (32x32x16, A=x regs, B=y from L2) ----------
// part[jc*N + i] = min_{j in chunk} (t[j] - 2<x_i,y_j>) = -2 max_j(<x_i,y_j>+th[j])
// R8: R7 (barrier-free, fragment-major coalesced L2 loads) + two latency levers:
//  (1) JC=16 -> 2048 blocks; residency now VGPR-limited (~5 waves/SIMD = 20/CU)
//      instead of grid-quantized at 16/CU, with dynamic refill (no tail rounds).
//  (2) rotated software pipeline: jj+1's B-frags/tl load BEFORE jj's MFMA+fmax
//      (named regs, plain HIP — R5 lesson: no asm, no full unroll).
// Floors per CU: MFMA 13.65 us, VALU ~15 us (fmax+cin inherent at D=64), L2 ~16 us.
__global__ __launch_bounds__(BLOCK, 2) void partial_min_kernel(
    const _Float16* __restrict__ xh, const _Float16* __restrict__ yhT,
    const float* __restrict__ th, float* __restrict__ part) {
    const int tid  = threadIdx.x;
    const int lane = tid & 63, wave = tid >> 6;
    const int hi = lane >> 5, r32 = lane & 31;
    const int jc    = blockIdx.y;
    const int jbase = jc * CHUNK;
    const int i_wave = blockIdx.x * ROWS_PER_BLOCK + wave * (GROUPS * 32);

    // x A-frags: 2 row-groups x 4 k-slices; lane holds row=r32, k=ks*16+hi*8+e
    v8h a[GROUPS][4];
#pragma unroll
    for (int g = 0; g < GROUPS; ++g) {
        const _Float16* px = xh + (size_t)(i_wave + g * 32 + r32) * D_DIM + hi * 8;
#pragma unroll
        for (int ks = 0; ks < 4; ++ks) a[g][ks] = *(const v8h*)(px + ks * 16);
    }

    // running elementwise max per group (element e -> row (e&3)+8*(e>>2)+4*hi)
    v16f vmax[GROUPS];
#pragma unroll
    for (int g = 0; g < GROUPS; ++g)
#pragma unroll
        for (int e = 0; e < 16; ++e) vmax[g][e] = -INFINITY;

    // per-lane fragment-major base: + jj*2048 walks 32-row j-blocks
    const _Float16* yb = yhT + (size_t)(jbase >> 5) * 2048 + hi * 256 + r32 * 8;
    const float*    tb = th + jbase + r32;

    // prologue: load jj=0's fragments
    v8h b0 = *(const v8h*)(yb);
    v8h b1 = *(const v8h*)(yb + 512);
    v8h b2 = *(const v8h*)(yb + 1024);
    v8h b3 = *(const v8h*)(yb + 1536);
    float tl = tb[0];

#pragma unroll 2
    for (int jj = 0; jj < NJJ; ++jj) {
        // prefetch jj+1 (clamped re-load of last tile on final iter: L1 hit, harmless)
        const int nx = (jj + 1 < NJJ) ? jj + 1 : jj;
        const _Float16* yn = yb + (size_t)nx * 2048;
        const v8h n0 = *(const v8h*)(yn);
        const v8h n1 = *(const v8h*)(yn + 512);
        const v8h n2 = *(const v8h*)(yn + 1024);
        const v8h n3 = *(const v8h*)(yn + 1536);
        const float tn = tb[nx * 32];

        v16f cin;
#pragma unroll
        for (int e = 0; e < 16; ++e) cin[e] = tl;   // splat: C-init = th[j]
        __builtin_amdgcn_s_setprio(1);
#pragma unroll
        for (int g = 0; g < GROUPS; ++g) {
            v16f acc = __builtin_amdgcn_mfma_f32_32x32x16_f16(a[g][0], b0, cin, 0, 0, 0);
            acc = __builtin_amdgcn_mfma_f32_32x32x16_f16(a[g][1], b1, acc, 0, 0, 0);
            acc = __builtin_amdgcn_mfma_f32_32x32x16_f16(a[g][2], b2, acc, 0, 0, 0);
            acc = __builtin_amdgcn_mfma_f32_32x32x16_f16(a[g][3], b3, acc, 0, 0, 0);
#pragma unroll
            for (int e = 0; e < 16; ++e)
                vmax[g][e] = fmaxf(vmax[g][e], acc[e]);
        }
        __builtin_amdgcn_s_setprio(0);

        b0 = n0; b1 = n1; b2 = n2; b3 = n3; tl = tn;   // rotate (renamed by unroll-2)
    }

    // epilogue (once per chunk): cross-lane max over the 32 j-col lanes, then store.
#pragma unroll
    for (int g = 0; g < GROUPS; ++g) {
#pragma unroll
        for (int e = 0; e < 16; ++e) {
            float v = vmax[g][e];
#pragma unroll
            for (int m = 1; m < 32; m <<= 1)
                v = fmaxf(v, __shfl_xor(v, m, 64));   // stays within 32-lane half
            vmax[g][e] = v;
        }
        // select element r32 via compile-time-indexed cndmask chain (no scratch)
        float v = vmax[g][0];
#pragma unroll
        for (int e = 1; e < 16; ++e) v = (r32 == e) ? vmax[g][e] : v;
        if (r32 < 16)
            part[(size_t)jc * N_ROWS + i_wave + g * 32
                 + (r32 & 3) + 8 * (r32 >> 2) + 4 * hi] = -2.f * v;
    }
}

// ---------- kernel 3: fused reduce ----------
// out += [ sum_i ( min_c part[c][i] + x2[i] ) ] / N + sum(psi) / M
__global__ __launch_bounds__(RBLOCK) void reduce_kernel(
    const float* __restrict__ part, const float* __restrict__ x2,
    const float* __restrict__ psi, float* __restrict__ out) {
    const int tid = threadIdx.x;
    const int gt  = blockIdx.x * RBLOCK + tid;    // [0, 32768)
    float m = part[gt];
#pragma unroll
    for (int c = 1; c < JC; ++c)
        m = fminf(m, part[(size_t)c * N_ROWS + gt]);
    float s = (m + x2[gt]) * (1.f / (float)N_ROWS);
    if (gt < M_COLS) s += psi[gt] * (1.f / (float)M_COLS);
    for (int off = 32; off > 0; off >>= 1) s += __shfl_down(s, off, 64);
    __shared__ float tmp[2];
    if ((tid & 63) == 0) tmp[tid >> 6] = s;
    __syncthreads();
    if (tid == 0) atomicAdd(out, tmp[0] + tmp[1]);
}

extern "C" void kernel_launch(void* const* d_in, const int* in_sizes, int n_in,
                              void* d_out, int out_size, void* d_ws, size_t ws_size,
                              hipStream_t stream) {
    const float* x   = (const float*)d_in[0];   // [N,D]
    const float* y   = (const float*)d_in[1];   // [M,D]
    const float* psi = (const float*)d_in[2];   // [M]
    float* out = (float*)d_out;

    // workspace layout
    float* part = (float*)d_ws;                            // JC*N floats = 2 MB
    float* th   = part + (size_t)JC * N_ROWS;              // M floats   = 32 KB
    float* x2   = th + (size_t)M_COLS;                     // N floats   = 128 KB
    _Float16* yhT = (_Float16*)(x2 + (size_t)N_ROWS);      // M*D halves = 1 MB
    _Float16* xh  = yhT + (size_t)M_COLS * D_DIM;          // N*D halves = 4 MB

    prep_kernel<<<(M_COLS + N_ROWS) / 16, PBLOCK, 0, stream>>>(y, psi, x, yhT, th, xh, x2, out);
    partial_min_kernel<<<dim3(N_ROWS / ROWS_PER_BLOCK, JC), BLOCK, 0, stream>>>(xh, yhT, th, part);
    reduce_kernel<<<N_ROWS / RBLOCK, RBLOCK, 0, stream>>>(part, x2, psi, out);
}